// Round 1
// baseline (488.965 us; speedup 1.0000x reference)
//
#include <hip/hip_runtime.h>
#include <math.h>

// ---------------------------------------------------------------------------
// JointsGait fused v4.
// layer = ReLU(((A_hat @ H) @ W + b) * att), A_hat constant 17x17.
//
// R5 restructure:
//  * Block = 2 graphs, rows padded to 24 (48 rows = 3 m-tiles of 16).
//  * H double-buffered in LDS: 2 x [48][256] f16 = 48 KB -> 3 blocks/CU
//    (12 waves/CU vs previous 8). launch_bounds(256,3).
//  * Double buffer removes the in-place hazard: the epilogue writes the
//    OTHER buffer, so no barrier between fragment reads and epilogue.
//    2 barriers/layer (was 3), 18 total (was 27).
//  * Swapped-operand MFMA: acc = mfma(bf, af) computes (H@W)^T, so each
//    lane holds one graph-row x 4 consecutive out-cols -> packed v4h
//    epilogue stores (12 ds_write_b64 vs 80 ds_write_u16 per big layer),
//    scalar att per lane (attp[g0*24 + r], linear), v4f bias loads.
//  * acc[3][4] = 48 regs (was 80) + af[3] = 12 (was 20): fits the
//    bounds-3 unified-file budget without spills (R4 lesson).
//  * Layer-1 K padded to 32 (DIN=2), not 64.
// ---------------------------------------------------------------------------

typedef _Float16 f16;
typedef _Float16 v2h __attribute__((ext_vector_type(2)));
typedef _Float16 v4h __attribute__((ext_vector_type(4)));
typedef _Float16 v8h __attribute__((ext_vector_type(8)));
typedef float    v4f __attribute__((ext_vector_type(4)));

namespace {

constexpr int BA[19] = {15,13,16,14,11, 5, 6, 5, 5, 6, 7, 8, 1, 0, 0, 1, 2, 3, 4};
constexpr int BB[19] = {13,11,14,12,12,11,12, 6, 7, 8, 9,10, 2, 1, 2, 3, 4, 5, 6};
constexpr float DINV[17] = {
  0.57735026919f, 0.5f, 0.5f, 0.57735026919f, 0.57735026919f,
  0.44721359550f, 0.44721359550f, 0.57735026919f, 0.57735026919f,
  0.70710678119f, 0.70710678119f, 0.5f, 0.5f,
  0.57735026919f, 0.57735026919f, 0.70710678119f, 0.70710678119f};

__device__ __forceinline__ void mix17(const float* h, float* g){
  #pragma unroll
  for (int i=0;i<17;i++) g[i] = (DINV[i]*DINV[i])*h[i];
  #pragma unroll
  for (int e=0;e<19;e++){
    const float c = DINV[BA[e]]*DINV[BB[e]];
    g[BA[e]] += c*h[BB[e]];
    g[BB[e]] += c*h[BA[e]];
  }
}

// H element index with XOR-chunk swizzle (row stride 256 f16 = 512B).
// Consistent on read and write; 3 LSBs of k preserved (v8h/v4h/v2h safe).
__device__ __forceinline__ int hswz(int row, int k){
  return row*256 + (k & ~63) + (((((k>>3)&7) ^ (row&7)))<<3) + (k&7);
}

__device__ __forceinline__ void ldh2(const f16* p, float* d){
  const v2h v = *(const v2h*)p; d[0]=v[0]; d[1]=v[1];
}

// ---- layer-1 init: H = A_hat @ x in cols 0..1, zeros in cols 2..31 ---------
// Also zeros pad rows (17..23 per graph) for cols 0..31. Cols >=32 never read
// in layer 1 (KP=32); W k-pad zeros protect everything downstream.
__device__ __forceinline__ void first_phase(f16* __restrict__ A,
    const float* __restrict__ x, int g0, int G, int t)
{
  const int g = t>>7, kk = t&127;
  if (kk >= 32) return;
  float h[17], gv[17];
  const bool live = (kk < 2) && (g0+g < G);
  #pragma unroll
  for (int i=0;i<17;++i) h[i] = live ? x[(size_t)(g0+g)*34 + i*2 + kk] : 0.f;
  mix17(h, gv);
  #pragma unroll
  for (int i=0;i<17;++i) A[hswz(g*24+i, kk)] = (f16)gv[i];
  #pragma unroll
  for (int j=17;j<24;++j) A[hswz(g*24+j, kk)] = (f16)0.f;
}

// ---- mix phase: H = A_hat @ H in place, v2h column pairs -------------------
// Thread-private columns: no intra-phase hazard. 128 threads/graph.
template<int KP>
__device__ __forceinline__ void mix_phase(f16* __restrict__ H, int t){
  const int g = t>>7, tt = t&127;
  if (tt >= KP/2) return;
  const int k0 = tt*2;
  float gv[34];
  #pragma unroll
  for (int i=0;i<34;++i) gv[i] = 0.f;
  #pragma unroll
  for (int i=0;i<17;++i){
    float hi[2];
    ldh2(H + hswz(g*24+i, k0), hi);
    const float dii = DINV[i]*DINV[i];
    gv[2*i]   += dii*hi[0];
    gv[2*i+1] += dii*hi[1];
    #pragma unroll
    for (int e=0;e<19;++e){
      const float c = DINV[BA[e]]*DINV[BB[e]];
      if (BA[e]==i){ gv[2*BB[e]] += c*hi[0]; gv[2*BB[e]+1] += c*hi[1]; }
      if (BB[e]==i){ gv[2*BA[e]] += c*hi[0]; gv[2*BA[e]+1] += c*hi[1]; }
    }
  }
  #pragma unroll
  for (int i=0;i<17;++i){
    v2h v; v[0]=(f16)gv[2*i]; v[1]=(f16)gv[2*i+1];
    *(v2h*)(H + hswz(g*24+i, k0)) = v;
  }
}

// ---- MFMA phase: dst = relu((src @ W + b)*att), swapped operands -----------
// mfma(bf, af): bf (Wt rows = out-cols) is the A operand, af (H rows) the B
// operand -> D[out_local][grow_local]: lane (q,m) holds rows r = mt*16+m of
// the graph slab and 4 consecutive out-cols c0 = cb + nt*16 + 4q.
// Epilogue writes the OTHER buffer: no barrier needed inside this phase.
template<int KP, int DOUT>
__device__ __forceinline__ void mfma_phase(const f16* __restrict__ src,
    f16* __restrict__ dst, const f16* __restrict__ Wt,
    const float* __restrict__ bias, const float* __restrict__ attp,
    int g0, int t)
{
  constexpr int NTW = DOUT/64;          // 16-wide n-tiles per wave (1x4 split)
  const int w = t>>6, lane = t&63, m = lane&15, q = lane>>4;
  const int cb = w*(DOUT/4);

  v4f acc[3][NTW];
  #pragma unroll
  for (int a=0;a<3;++a)
    #pragma unroll
    for (int b=0;b<NTW;++b) acc[a][b] = v4f{0.f,0.f,0.f,0.f};

  #pragma unroll
  for (int ks=0; ks<KP/32; ++ks){
    v8h af[3];
    #pragma unroll
    for (int mt=0;mt<3;++mt)
      af[mt] = *(const v8h*)(src + hswz(mt*16+m, ks*32 + q*8));
    #pragma unroll
    for (int nt=0;nt<NTW;++nt){
      const v8h bf = *(const v8h*)(Wt + (size_t)(cb+nt*16+m)*KP + ks*32 + q*8);
      #pragma unroll
      for (int mt=0;mt<3;++mt)
        acc[mt][nt] = __builtin_amdgcn_mfma_f32_16x16x32_f16(bf, af[mt], acc[mt][nt], 0,0,0);
    }
  }

  // epilogue: row r is linear in attp (stride-24 padded graphs, pad att = 0)
  #pragma unroll
  for (int mt=0;mt<3;++mt){
    const int r = mt*16 + m;
    const float av = attp[(size_t)g0*24 + r];
    #pragma unroll
    for (int nt=0;nt<NTW;++nt){
      const int c0 = cb + nt*16 + 4*q;
      const v4f b4 = *(const v4f*)(bias + c0);
      v4h o;
      #pragma unroll
      for (int i=0;i<4;++i)
        o[i] = (f16)fmaxf((acc[mt][nt][i] + b4[i])*av, 0.f);
      *(v4h*)(dst + hswz(r, c0)) = o;
    }
  }
}

} // namespace

// ---------------- prep: f16 W^T (k-padded), f16 fcW, BN fold, padded att -----
__global__ void prep_kernel(
    const float* __restrict__ W1, const float* __restrict__ W2,
    const float* __restrict__ W3, const float* __restrict__ W4,
    const float* __restrict__ W5, const float* __restrict__ W6,
    const float* __restrict__ W7, const float* __restrict__ W8,
    const float* __restrict__ W9,
    const float* __restrict__ fcW, const float* __restrict__ bng,
    const float* __restrict__ bnb, const float* __restrict__ bnrm,
    const float* __restrict__ bnrv, const float* __restrict__ att,
    f16* __restrict__ wt, f16* __restrict__ fcWh,
    float* __restrict__ bnsc, float* __restrict__ bnsh,
    float* __restrict__ attp, int G)
{
  const int idx = blockIdx.x*blockDim.x + threadIdx.x;
  const int stride = gridDim.x*blockDim.x;
  const float* Ws[9] = {W1,W2,W3,W4,W5,W6,W7,W8,W9};
  const int DINs[9]  = {2,64,64,64,128,128,128,256,256};
  const int DOUTs[9] = {64,64,64,128,128,128,256,256,256};
  const int KPs[9]   = {32,64,64,64,128,128,128,256,256};
  const int OFFs[9]  = {0,2048,6144,10240,18432,34816,51200,83968,149504};
  for (int l=0;l<9;++l){
    const float* W = Ws[l];
    const int DIN=DINs[l], DOUT=DOUTs[l], KP=KPs[l];
    f16* dst = wt + OFFs[l];
    const int n = DOUT*KP;
    for (int i=idx;i<n;i+=stride){
      const int row = i/KP, k = i - row*KP;           // row = out index
      dst[i] = (k<DIN) ? (f16)W[k*DOUT+row] : (f16)0.f;
    }
  }
  for (int i=idx;i<6*256*256;i+=stride) fcWh[i] = (f16)fcW[i];
  for (int i=idx;i<1536;i+=stride){
    const float sc = bng[i] * rsqrtf(bnrv[i] + 1e-5f);
    bnsc[i] = sc; bnsh[i] = bnb[i] - bnrm[i]*sc;
  }
  const int G2 = (G+1)&~1;
  for (int i=idx;i<G2*24;i+=stride){
    const int g = i/24, j = i - g*24;
    attp[i] = (j<17 && g<G) ? att[(size_t)g*17 + j] : 0.f;
  }
}

// ---------------- fused GCN (9 layers) + pooling -----------------------------
__global__ __launch_bounds__(256, 3)
void gcn_kernel(const float* __restrict__ x, const f16* __restrict__ wt,
                const float* __restrict__ attp,
                const float* __restrict__ b1, const float* __restrict__ b2,
                const float* __restrict__ b3, const float* __restrict__ b4,
                const float* __restrict__ b5, const float* __restrict__ b6,
                const float* __restrict__ b7, const float* __restrict__ b8,
                const float* __restrict__ b9,
                f16* __restrict__ pooled, int G)
{
  __shared__ __align__(16) f16 Hb[2][48*256];   // 2 x 24576 B = 48 KB
  const int t = threadIdx.x;
  const int g0 = blockIdx.x*2;
  f16* A = Hb[0]; f16* B = Hb[1];

  first_phase(A, x, g0, G, t);
  __syncthreads();
  mfma_phase< 32, 64>(A, B, wt+0,      b1, attp, g0, t); __syncthreads();
  mix_phase< 64>(B, t); __syncthreads();
  mfma_phase< 64, 64>(B, A, wt+2048,   b2, attp, g0, t); __syncthreads();
  mix_phase< 64>(A, t); __syncthreads();
  mfma_phase< 64, 64>(A, B, wt+6144,   b3, attp, g0, t); __syncthreads();
  mix_phase< 64>(B, t); __syncthreads();
  mfma_phase< 64,128>(B, A, wt+10240,  b4, attp, g0, t); __syncthreads();
  mix_phase<128>(A, t); __syncthreads();
  mfma_phase<128,128>(A, B, wt+18432,  b5, attp, g0, t); __syncthreads();
  mix_phase<128>(B, t); __syncthreads();
  mfma_phase<128,128>(B, A, wt+34816,  b6, attp, g0, t); __syncthreads();
  mix_phase<128>(A, t); __syncthreads();
  mfma_phase<128,256>(A, B, wt+51200,  b7, attp, g0, t); __syncthreads();
  mix_phase<256>(B, t); __syncthreads();
  mfma_phase<256,256>(B, A, wt+83968,  b8, attp, g0, t); __syncthreads();
  mix_phase<256>(A, t); __syncthreads();
  mfma_phase<256,256>(A, B, wt+149504, b9, attp, g0, t); __syncthreads();

  // ---- JRPP pooling from B: v2h column pairs, 128 threads/graph -----------
  const int g = t>>7, tt = t&127, k0 = tt*2, gg = g0 + g;
  if (gg < G){
    float sA[2]={0,0}, sB[2]={0,0}, sH[2]={0,0}, sL[2]={0,0}, sR[2]={0,0};
    #pragma unroll
    for (int i=0;i<17;++i){
      float hi[2];
      ldh2(B + hswz(g*24+i, k0), hi);
      #pragma unroll
      for (int v=0;v<2;++v){
        if (i<11) sA[v]+=hi[v]; else sB[v]+=hi[v];
        if (i<5)  sH[v]+=hi[v];
        if (i==5||i==7||i==9||i==12||i==14||i==16)  sL[v]+=hi[v];
        if (i==6||i==8||i==10||i==11||i==13||i==15) sR[v]+=hi[v];
      }
    }
    f16* op = pooled + (size_t)gg*1536 + k0;
    v2h o;
    #pragma unroll
    for (int v=0;v<2;++v) o[v]=(f16)((sA[v]+sB[v])*(1.0f/17.0f)); *(v2h*)(op+0*256)=o;
    #pragma unroll
    for (int v=0;v<2;++v) o[v]=(f16)(sA[v]*(1.0f/11.0f));         *(v2h*)(op+1*256)=o;
    #pragma unroll
    for (int v=0;v<2;++v) o[v]=(f16)(sB[v]*(1.0f/6.0f));          *(v2h*)(op+2*256)=o;
    #pragma unroll
    for (int v=0;v<2;++v) o[v]=(f16)(sH[v]*(1.0f/5.0f));          *(v2h*)(op+3*256)=o;
    #pragma unroll
    for (int v=0;v<2;++v) o[v]=(f16)(sL[v]*(1.0f/6.0f));          *(v2h*)(op+4*256)=o;
    #pragma unroll
    for (int v=0;v<2;++v) o[v]=(f16)(sR[v]*(1.0f/6.0f));          *(v2h*)(op+5*256)=o;
  }
}

// ---------------- head: stage once, 288 MFMA straight-line, BN + L2-norm -----
__global__ __launch_bounds__(256, 2)
void head_kernel(const f16* __restrict__ pooled, const f16* __restrict__ fcWh,
                 const float* __restrict__ fcB, const float* __restrict__ bnsc,
                 const float* __restrict__ bnsh, float* __restrict__ out, int G)
{
  __shared__ __align__(16) f16 Ap[16*1536];   // 49152 B, swizzled
  __shared__ float red[64];
  __shared__ float invn[16];
  const int t = threadIdx.x, w = t>>6, lane = t&63;
  const int m = lane&15, q = lane>>4;
  const int g0 = blockIdx.x*16;
  const int cb = w*64;

  // stage pooled rows (all 6 scales) once
  for (int id=t; id<16*192; id+=256){
    const int row = id/192, cc = id - row*192;
    v8h v = v8h{0,0,0,0,0,0,0,0};
    const int gg = g0 + row;
    if (gg < G) v = *(const v8h*)(pooled + (size_t)gg*1536 + cc*8);
    const int pc = (cc & ~7) | ((cc&7) ^ (row&7));
    *(v8h*)(Ap + row*1536 + pc*8) = v;
  }
  __syncthreads();

  v4f acc[6][4];
  #pragma unroll
  for (int s=0;s<6;++s)
    #pragma unroll
    for (int nt=0;nt<4;++nt) acc[s][nt] = v4f{0.f,0.f,0.f,0.f};

  #pragma unroll
  for (int s=0;s<6;++s){
    #pragma unroll
    for (int ks=0; ks<8; ++ks){
      const int c = s*32 + ks*4 + q;
      const v8h af = *(const v8h*)(Ap + m*1536 + ((c & ~7) | ((c&7) ^ (m&7)))*8);
      #pragma unroll
      for (int nt=0;nt<4;++nt){
        const v8h bf = *(const v8h*)(fcWh + (size_t)(s*256 + cb + nt*16 + m)*256 + ks*32 + q*8);
        acc[s][nt] = __builtin_amdgcn_mfma_f32_16x16x32_f16(af, bf, acc[s][nt], 0,0,0);
      }
    }
  }

  // BN in place + per-graph sum of squares
  float ss[4] = {0.f,0.f,0.f,0.f};
  #pragma unroll
  for (int s=0;s<6;++s)
    #pragma unroll
    for (int nt=0;nt<4;++nt){
      const int idx = s*256 + cb + nt*16 + m;
      const float bc = fcB[idx], sc = bnsc[idx], sh = bnsh[idx];
      #pragma unroll
      for (int i=0;i<4;++i){
        const float f = (acc[s][nt][i] + bc)*sc + sh;
        acc[s][nt][i] = f;
        ss[i] += f*f;
      }
    }

  #pragma unroll
  for (int off=1; off<16; off<<=1)
    #pragma unroll
    for (int i=0;i<4;++i) ss[i] += __shfl_xor(ss[i], off, 64);
  if (m==0)
    #pragma unroll
    for (int i=0;i<4;++i) red[w*16 + q*4 + i] = ss[i];
  __syncthreads();
  if (t < 16){
    const float s4 = red[t] + red[16+t] + red[32+t] + red[48+t];
    invn[t] = 1.f / fmaxf(sqrtf(s4), 1e-12f);
  }
  __syncthreads();
  float iv[4];
  #pragma unroll
  for (int i=0;i<4;++i) iv[i] = invn[q*4+i];
  #pragma unroll
  for (int s=0;s<6;++s)
    #pragma unroll
    for (int nt=0;nt<4;++nt)
      #pragma unroll
      for (int i=0;i<4;++i){
        const int gg = g0 + q*4 + i;
        if (gg < G)
          out[(size_t)gg*1536 + s*256 + cb + nt*16 + m] = acc[s][nt][i]*iv[i];
      }
}

extern "C" void kernel_launch(void* const* d_in, const int* in_sizes, int n_in,
                              void* d_out, int out_size, void* d_ws, size_t ws_size,
                              hipStream_t stream) {
  (void)n_in; (void)out_size; (void)ws_size;
  const float* x   = (const float*)d_in[0];
  const float* att = (const float*)d_in[1];
  const float* W[9]; const float* B[9];
  for (int i=0;i<9;i++){ W[i]=(const float*)d_in[3+2*i]; B[i]=(const float*)d_in[4+2*i]; }
  const float* fcW  = (const float*)d_in[21];
  const float* fcB  = (const float*)d_in[22];
  const float* bn_g = (const float*)d_in[23];
  const float* bn_b = (const float*)d_in[24];
  const float* bn_rm= (const float*)d_in[25];
  const float* bn_rv= (const float*)d_in[26];
  float* out = (float*)d_out;

  const int G = in_sizes[1] / 17;
  const int G2 = (G+1)&~1;

  // ws layout
  char* ws = (char*)d_ws;
  f16*   wt   = (f16*)(ws);                       // 430080 B (215040 f16)
  f16*   fcWh = (f16*)(ws + 430080);              // 786432 B
  float* bnsc = (float*)(ws + 1216512);           // 6144 B
  float* bnsh = (float*)(ws + 1222656);           // 6144 B
  float* attp = (float*)(ws + 1228800);           // G2*24*4 B
  size_t poolOff = (1228800 + (size_t)G2*96 + 255) & ~(size_t)255;
  f16* pooled = (f16*)(ws + poolOff);             // G*1536*2 B

  prep_kernel<<<256, 256, 0, stream>>>(
      W[0],W[1],W[2],W[3],W[4],W[5],W[6],W[7],W[8],
      fcW, bn_g, bn_b, bn_rm, bn_rv, att,
      wt, fcWh, bnsc, bnsh, attp, G);

  const int gb = (G + 1) / 2;
  gcn_kernel<<<gb, 256, 0, stream>>>(
      x, wt, attp,
      B[0],B[1],B[2],B[3],B[4],B[5],B[6],B[7],B[8],
      pooled, G);

  head_kernel<<<(G + 15)/16, 256, 0, stream>>>(
      pooled, fcWh, fcB, bnsc, bnsh, out, G);
}